// Round 8
// baseline (1403.973 us; speedup 1.0000x reference)
//
#include <hip/hip_runtime.h>
#include <stdint.h>
#include <stddef.h>

#define BB 8
#define NN 4096
#define MTOK 1024
#define DD 1024
#define HH 16
#define EPSF 1e-6f
static const float SCALE_F = 0.125f; // HD^-0.5, HD=64

typedef __attribute__((ext_vector_type(4))) float f32x4;
typedef __attribute__((ext_vector_type(8))) short bf16x8;

__device__ __forceinline__ short f2bf(float f) {
  union { float f; uint32_t u; } x; x.f = f;
  uint32_t r = (x.u + 0x7fffu + ((x.u >> 16) & 1u)) >> 16;
  return (short)(uint16_t)r;
}
__device__ __forceinline__ float bf2f(short s) {
  union { uint32_t u; float f; } x; x.u = ((uint32_t)(uint16_t)s) << 16;
  return x.f;
}

#if defined(__HIP_DEVICE_COMPILE__) && __has_builtin(__builtin_amdgcn_global_load_lds)
#define USE_GLOAD_LDS 1
#else
#define USE_GLOAD_LDS 0
#endif

#define BAR() __builtin_amdgcn_s_barrier()
#define LGKM0()                                        \
  do {                                                 \
    asm volatile("s_waitcnt lgkmcnt(0)" ::: "memory"); \
    __builtin_amdgcn_sched_barrier(0);                 \
  } while (0)
#if USE_GLOAD_LDS
#define VMW4() asm volatile("s_waitcnt vmcnt(4)" ::: "memory")
#else
#define VMW4() asm volatile("s_waitcnt vmcnt(0) lgkmcnt(0)" ::: "memory")
#endif
#define VMW0() asm volatile("s_waitcnt vmcnt(0)" ::: "memory")

// ---------------------------------------------------------------------------
// 128x128 bf16 GEMM, BK=64, 8 waves (2M x 4N) of 64x32, LDS 64 KiB
// (2 bufs x {A 16K, B 16K}) -> 2 blocks/CU co-resident (the m97/m114
// cross-block overlap mechanism), ~110 VGPR target via small acc (32).
// Swizzle byte ^= ((byte>>7)&7)<<4 on ds_read addrs + pre-swizzled global
// stage source (linear global_load_lds dest) — 0 bank conflicts (round-3).
// K-tile t (buf = t&1):
//   P1: rd 12 (A 8, B 4) ; lgkm0+schedbar ; setprio{8 MFMA n=0} ; barrier
//   P2: stage tile t+2 -> buf (4 gload_lds) ; vmcnt(4) ; setprio{8 MFMA n=1}
//       ; barrier
// Invariants: stage issues after the barrier closing ALL reads of its dest
// buffer; reads of tile t+1 are covered by iter t's vmcnt(4)+barrier
// (stage(t+1) issued at t-1 P2; outstanding at t P2 <= 8 -> vmcnt(4) drains
// it). Prologue stages tiles 0,1 + vmcnt(4). T = K/64 >= 3 always here.
// EPI: 0 f32 acc+bias | 1 f32 acc+bias+resid | 2 bf16 acc+bias | 3 bf16 silu
// ---------------------------------------------------------------------------
__device__ __forceinline__ void stg2(char* smc, int ldsbase, const short* pg,
                                     int ld, int k, int w) {
#pragma unroll
  for (int i = 0; i < 2; ++i) {
    const short* src = pg + (long)(i * 64) * ld + k;
    char* dst = smc + ldsbase + i * 8192 + w * 1024;
#if USE_GLOAD_LDS
    __builtin_amdgcn_global_load_lds(
        (const __attribute__((address_space(1))) void*)src,
        (__attribute__((address_space(3))) void*)dst, 16, 0, 0);
#else
    *(bf16x8*)(dst + (int)(threadIdx.x & 63) * 16) = *(const bf16x8*)src;
#endif
  }
}
template <int NH>
__device__ __forceinline__ void mq8(const bf16x8 a[4][2], const bf16x8 b[2][2],
                                    f32x4 acc[4][2]) {
  __builtin_amdgcn_s_setprio(1);
#pragma unroll
  for (int m = 0; m < 4; ++m) {
    f32x4 c = acc[m][NH];
    c = __builtin_amdgcn_mfma_f32_16x16x32_bf16(a[m][0], b[NH][0], c, 0, 0, 0);
    c = __builtin_amdgcn_mfma_f32_16x16x32_bf16(a[m][1], b[NH][1], c, 0, 0, 0);
    acc[m][NH] = c;
  }
  __builtin_amdgcn_s_setprio(0);
}

template <int EPI>
__global__ __launch_bounds__(512, 4) void gemm128(
    const short* __restrict__ A, const short* __restrict__ BT,
    const float* __restrict__ bias, const float* __restrict__ resid,
    void* __restrict__ outp, int N, int K, int lda, int ldb, int num_n) {
  __shared__ int4 smem4[65536 / 16];
  char* smc = (char*)smem4;
  const int t = threadIdx.x;
  const int w = t >> 6, lane = t & 63;
  const int wr = w >> 2, wc = w & 3;

  // bijective XCD swizzle (m204)
  const int nwg = gridDim.x, orig = blockIdx.x;
  const int q8 = nwg >> 3, r8 = nwg & 7;
  const int xcd = orig & 7, loc = orig >> 3;
  const int wg = (xcd < r8 ? xcd * (q8 + 1) : r8 * (q8 + 1) + (xcd - r8) * q8) + loc;
  // row-major tile mapping: consecutive wg (same XCD) share the A panel
  const int bm = wg / num_n, bn = wg % num_n;

  const int T = K >> 6;

  // swizzled ds_read byte offsets (ks=1 = ^64)
  int LA = (wr * 64 + (lane & 15)) * 128 + ((lane >> 4) << 4);
  LA ^= ((LA >> 7) & 7) << 4;
  int LB = (wc * 32 + (lane & 15)) * 128 + ((lane >> 4) << 4);
  LB ^= ((LB >> 7) & 7) << 4;

  // pre-swizzled global stage source (row = t>>3 (+64), col slot ^ row&7)
  const int colswz = ((t & 7) ^ ((t >> 3) & 7)) * 8;
  const short* pAg = A + (long)(bm * 128 + (t >> 3)) * lda + colswz;
  const short* pBg = BT + (long)(bn * 128 + (t >> 3)) * ldb + colswz;

  f32x4 acc[4][2];
#pragma unroll
  for (int i = 0; i < 4; ++i) {
    acc[i][0] = (f32x4){0.f, 0.f, 0.f, 0.f};
    acc[i][1] = (f32x4){0.f, 0.f, 0.f, 0.f};
  }
  bf16x8 a[4][2], b[2][2];

  // prologue: tile0 -> buf0, tile1 -> buf1
  stg2(smc, 0, pAg, lda, 0, w);
  stg2(smc, 16384, pBg, ldb, 0, w);
  stg2(smc, 32768, pAg, lda, 64, w);
  stg2(smc, 49152, pBg, ldb, 64, w);
  VMW4();  // tile0's 4 loads done
  BAR();

  for (int kt = 0; kt < T; ++kt) {
    const int bb = (kt & 1) * 32768;
    const int kpre = (kt + 2 < T ? kt + 2 : 0) * 64;
    // P1: reads + MFMA(n=0)
#pragma unroll
    for (int m = 0; m < 4; ++m) {
      a[m][0] = *(const bf16x8*)(smc + bb + LA + m * 2048);
      a[m][1] = *(const bf16x8*)(smc + bb + (LA ^ 64) + m * 2048);
    }
#pragma unroll
    for (int n = 0; n < 2; ++n) {
      b[n][0] = *(const bf16x8*)(smc + bb + 16384 + LB + n * 2048);
      b[n][1] = *(const bf16x8*)(smc + bb + 16384 + (LB ^ 64) + n * 2048);
    }
    LGKM0();
    mq8<0>(a, b, acc);
    BAR();  // all waves' reads of buf bb complete
    // P2: stage tile kt+2 into buf bb, wait stage(kt+1), MFMA(n=1)
    stg2(smc, bb, pAg, lda, kpre, w);
    stg2(smc, bb + 16384, pBg, ldb, kpre, w);
    VMW4();  // stage(kt+1) (issued last iter) complete
    mq8<1>(a, b, acc);
    BAR();  // next iter's reads may begin
  }
  VMW0();

  // epilogue: wave block = rows [wr*64, +64), cols [wc*32, +32)
  const int r0 = bm * 128 + wr * 64 + ((lane >> 4) << 2);
  const int c0 = bn * 128 + wc * 32 + (lane & 15);
#pragma unroll
  for (int mi = 0; mi < 4; ++mi) {
#pragma unroll
    for (int ni = 0; ni < 2; ++ni) {
      const int col = c0 + ni * 16;
      const float bv = bias ? bias[col] : 0.f;
#pragma unroll
      for (int rr = 0; rr < 4; ++rr) {
        const int row = r0 + mi * 16 + rr;
        const long idx = (long)row * N + col;
        float v = acc[mi][ni][rr] + bv;
        if (EPI == 0) {
          ((float*)outp)[idx] = v;
        } else if (EPI == 1) {
          ((float*)outp)[idx] = v + resid[idx];
        } else if (EPI == 2) {
          ((short*)outp)[idx] = f2bf(v);
        } else {
          v = v / (1.f + __expf(-v));
          ((short*)outp)[idx] = f2bf(v);
        }
      }
    }
  }
}

// ---------------------------------------------------------------------------
// Row LayerNorm over D=1024, fp32 in -> bf16 out. One block (256 thr) per row.
// ---------------------------------------------------------------------------
__global__ __launch_bounds__(256) void ln_rows(const float* __restrict__ in,
                                               const float* __restrict__ g,
                                               const float* __restrict__ bta,
                                               short* __restrict__ outp) {
  const int row = blockIdx.x;
  const int t = threadIdx.x;
  const float4 v = ((const float4*)(in + (long)row * DD))[t];
  float s = v.x + v.y + v.z + v.w;
  float ss = v.x * v.x + v.y * v.y + v.z * v.z + v.w * v.w;
#pragma unroll
  for (int off = 1; off < 64; off <<= 1) {
    s += __shfl_xor(s, off);
    ss += __shfl_xor(ss, off);
  }
  __shared__ float red[8];
  const int w = t >> 6, lane = t & 63;
  if (lane == 0) { red[w] = s; red[4 + w] = ss; }
  __syncthreads();
  s = red[0] + red[1] + red[2] + red[3];
  ss = red[4] + red[5] + red[6] + red[7];
  const float mu = s * (1.f / DD);
  const float var = ss * (1.f / DD) - mu * mu;
  const float rs = rsqrtf(var + EPSF);
  const float4 gv = ((const float4*)g)[t];
  const float4 bv = ((const float4*)bta)[t];
  short4 o;
  o.x = f2bf((v.x - mu) * rs * gv.x + bv.x);
  o.y = f2bf((v.y - mu) * rs * gv.y + bv.y);
  o.z = f2bf((v.z - mu) * rs * gv.z + bv.z);
  o.w = f2bf((v.w - mu) * rs * gv.w + bv.w);
  ((short4*)(outp + (long)row * DD))[t] = o;
}

// ---------------------------------------------------------------------------
// Transpose + fp32->bf16 convert: W[K][N] -> WT[N][K]. 64x64 tiles.
// ---------------------------------------------------------------------------
__global__ __launch_bounds__(256) void tconv(const float* __restrict__ W,
                                             short* __restrict__ WT, int K, int N) {
  __shared__ float tile[64][65];
  const int k0 = blockIdx.x * 64, n0 = blockIdx.y * 64;
  const int t = threadIdx.x;
  const int tr = t >> 6, tc = t & 63;
#pragma unroll
  for (int i = 0; i < 64; i += 4)
    tile[i + tr][tc] = W[(long)(k0 + i + tr) * N + n0 + tc];
  __syncthreads();
#pragma unroll
  for (int i = 0; i < 64; i += 4)
    WT[(long)(n0 + i + tr) * K + k0 + tc] = f2bf(tile[tc][i + tr]);
}

// ---------------------------------------------------------------------------
// ctx[b,h,d,e] = sum_m softmax_d(k[b,m,h,:])[d] * v[b,m,h,e].
// ---------------------------------------------------------------------------
__global__ __launch_bounds__(256) void ctx_kernel(const short* __restrict__ kv,
                                                  float* __restrict__ ctx) {
  const int bh = blockIdx.x;
  const int b = bh >> 4, h = bh & 15;
  const int t = threadIdx.x, g = t >> 6, lane = t & 63;
  __shared__ float ksm[4][64];
  __shared__ float vsm[4][64];
  float acc[16];
#pragma unroll
  for (int j = 0; j < 16; ++j) acc[j] = 0.f;
  const int d = t & 63;
  const int e0 = (t >> 6) * 16;
  const short* base = kv + (long)b * MTOK * 2048 + h * 64;
  for (int m0 = 0; m0 < MTOK; m0 += 4) {
    const long moff = (long)(m0 + g) * 2048;
    float kval = bf2f(base[moff + lane]);
    float vval = bf2f(base[moff + 1024 + lane]);
    float mx = kval;
#pragma unroll
    for (int off = 1; off < 64; off <<= 1) mx = fmaxf(mx, __shfl_xor(mx, off));
    float e = __expf(kval - mx);
    float sm = e;
#pragma unroll
    for (int off = 1; off < 64; off <<= 1) sm += __shfl_xor(sm, off);
    ksm[g][lane] = e / sm;
    vsm[g][lane] = vval;
    __syncthreads();
#pragma unroll
    for (int mm = 0; mm < 4; ++mm) {
      const float kd = ksm[mm][d];
#pragma unroll
      for (int j = 0; j < 16; ++j) acc[j] = fmaf(kd, vsm[mm][e0 + j], acc[j]);
    }
    __syncthreads();
  }
  float* cp = ctx + ((long)bh * 64 + d) * 64 + e0;
#pragma unroll
  for (int j = 0; j < 16; ++j) cp[j] = acc[j];
}

// ---------------------------------------------------------------------------
// Column softmax stats for q (softmax over the N axis per (b, column)).
// ---------------------------------------------------------------------------
__global__ __launch_bounds__(256) void qstat_part(const float* __restrict__ q,
                                                  float* __restrict__ pmax,
                                                  float* __restrict__ psum) {
  const int c = blockIdx.x * 256 + threadIdx.x;
  const int b = blockIdx.z, ch = blockIdx.y;
  const float* qp = q + ((long)b * NN + ch * 128) * DD + c;
  float mx = -1e30f, sm = 0.f;
  for (int r = 0; r < 128; ++r) {
    const float xv = qp[(long)r * DD];
    const float nm = fmaxf(mx, xv);
    sm = sm * __expf(mx - nm) + __expf(xv - nm);
    mx = nm;
  }
  const long idx = ((long)b * DD + c) * 32 + ch;
  pmax[idx] = mx;
  psum[idx] = sm;
}

__global__ __launch_bounds__(256) void qstat_comb(const float* __restrict__ pmax,
                                                  const float* __restrict__ psum,
                                                  float* __restrict__ cmax,
                                                  float* __restrict__ crs) {
  const int i = blockIdx.x * 256 + threadIdx.x;  // b*1024 + c
  const float* pm = pmax + (long)i * 32;
  const float* ps = psum + (long)i * 32;
  float mx = -1e30f;
#pragma unroll
  for (int ch = 0; ch < 32; ++ch) mx = fmaxf(mx, pm[ch]);
  float sm = 0.f;
#pragma unroll
  for (int ch = 0; ch < 32; ++ch) sm += ps[ch] * __expf(pm[ch] - mx);
  cmax[i] = mx;
  crs[i] = SCALE_F / sm;
}

// ---------------------------------------------------------------------------
// Fused: q_soft = exp(q-cmax)*crs (includes SCALE), out = q_soft @ ctx[b,h].
// ---------------------------------------------------------------------------
__global__ __launch_bounds__(256) void attn_apply(const float* __restrict__ q,
                                                  const float* __restrict__ ctx,
                                                  const float* __restrict__ cmax,
                                                  const float* __restrict__ crs,
                                                  short* __restrict__ outa) {
  const int b = blockIdx.z, h = blockIdx.y, n0 = blockIdx.x * 128;
  const int t = threadIdx.x, g = t >> 6, lane = t & 63;
  __shared__ float ctx_l[4096];
  __shared__ float cm[64], cs[64];
  __shared__ float qsm[4][64];
  const float* cp = ctx + (long)(b * HH + h) * 4096;
  for (int i = t; i < 4096; i += 256) ctx_l[i] = cp[i];
  if (t < 64) {
    cm[t] = cmax[(long)b * DD + h * 64 + t];
    cs[t] = crs[(long)b * DD + h * 64 + t];
  }
  __syncthreads();
  for (int i = 0; i < 32; ++i) {
    const int n = n0 + i * 4 + g;
    const long off = ((long)b * NN + n) * DD + h * 64;
    const float qv = q[off + lane];
    const float qs = __expf(qv - cm[lane]) * cs[lane];
    qsm[g][lane] = qs;  // same-wave LDS, no barrier needed
    float o = 0.f;
#pragma unroll
    for (int dd = 0; dd < 64; ++dd) o = fmaf(qsm[g][dd], ctx_l[dd * 64 + lane], o);
    outa[off + lane] = f2bf(o);
  }
}

// ---------------------------------------------------------------------------
extern "C" void kernel_launch(void* const* d_in, const int* in_sizes, int n_in,
                              void* d_out, int out_size, void* d_ws, size_t ws_size,
                              hipStream_t stream) {
  (void)in_sizes; (void)n_in; (void)out_size;
  const float* x      = (const float*)d_in[0];
  const float* wav    = (const float*)d_in[1];
  const float* ln_q_g = (const float*)d_in[2];
  const float* ln_q_b = (const float*)d_in[3];
  const float* Wq     = (const float*)d_in[4];
  const float* bq     = (const float*)d_in[5];
  const float* ln_kv_g= (const float*)d_in[6];
  const float* ln_kv_b= (const float*)d_in[7];
  const float* Wkv    = (const float*)d_in[8];
  const float* bkv    = (const float*)d_in[9];
  const float* Wo     = (const float*)d_in[10];
  const float* bo     = (const float*)d_in[11];
  const float* ln_f_g = (const float*)d_in[12];
  const float* ln_f_b = (const float*)d_in[13];
  const float* W1     = (const float*)d_in[14];
  const float* b1     = (const float*)d_in[15];
  const float* W2     = (const float*)d_in[16];
  const float* b2     = (const float*)d_in[17];
  float* outp = (float*)d_out;
  char* ws = (char*)d_ws;

  const long MR = (long)BB * NN;    // 32768 rows
  const long MKV = (long)BB * MTOK; // 8192 rows

  size_t off = 0;
  auto bump = [&](size_t bytes) {
    size_t o = off;
    off += (bytes + 255) & ~(size_t)255;
    return o;
  };
  short* WqT  = (short*)(ws + bump((size_t)DD * DD * 2));
  short* WkvT = (short*)(ws + bump((size_t)2048 * DD * 2));
  short* WoT  = (short*)(ws + bump((size_t)DD * DD * 2));
  short* W1T  = (short*)(ws + bump((size_t)4096 * DD * 2));
  short* W2T  = (short*)(ws + bump((size_t)DD * 4096 * 2));
  float* qbuf = (float*)(ws + bump((size_t)MR * DD * 4));   // later: x2 (fp32)
  short* lnbuf= (short*)(ws + bump((size_t)MR * DD * 2));   // xq_ln, later x2_ln
  float* ctx  = (float*)(ws + bump((size_t)BB * HH * 64 * 64 * 4));
  float* pmax = (float*)(ws + bump((size_t)BB * DD * 32 * 4));
  float* psum = (float*)(ws + bump((size_t)BB * DD * 32 * 4));
  float* cmax = (float*)(ws + bump((size_t)BB * DD * 4));
  float* crs  = (float*)(ws + bump((size_t)BB * DD * 4));
  const size_t dyn0 = off;
  short* wvln  = (short*)(ws + dyn0);
  short* kvbuf = (short*)(ws + dyn0 + (size_t)MKV * DD * 2);
  short* oattn = (short*)(ws + dyn0);  // reuses wvln+kv region (dead by then)
  short* hbuf  = (short*)(ws + dyn0);  // MLP phase (oattn dead by then)

  size_t avail = ws_size > dyn0 ? ws_size - dyn0 : 0;
  int CS = 4096;
  while (CS > 256 && (size_t)MR * CS * 2 > avail) CS >>= 1;

  const int nm = (int)(MR / 128);    // 256
  const int nmkv = (int)(MKV / 128); // 64

  // 1) weight convert+transpose to bf16 [N][K]
  tconv<<<dim3(DD / 64, DD / 64), 256, 0, stream>>>(Wq, WqT, DD, DD);
  tconv<<<dim3(DD / 64, 2048 / 64), 256, 0, stream>>>(Wkv, WkvT, DD, 2048);
  tconv<<<dim3(DD / 64, DD / 64), 256, 0, stream>>>(Wo, WoT, DD, DD);
  tconv<<<dim3(DD / 64, 4096 / 64), 256, 0, stream>>>(W1, W1T, DD, 4096);
  tconv<<<dim3(4096 / 64, DD / 64), 256, 0, stream>>>(W2, W2T, 4096, DD);

  // 2) LayerNorms -> bf16
  ln_rows<<<dim3((unsigned)MR), 256, 0, stream>>>(x, ln_q_g, ln_q_b, lnbuf);
  ln_rows<<<dim3((unsigned)MKV), 256, 0, stream>>>(wav, ln_kv_g, ln_kv_b, wvln);

  // 3) q = LN(x) @ Wq + bq   (fp32 out, needed for column softmax)
  gemm128<0><<<dim3((unsigned)(nm * (DD / 128))), 512, 0, stream>>>(
      lnbuf, WqT, bq, nullptr, qbuf, DD, DD, DD, DD, DD / 128);
  // 4) kv = LN(wav) @ Wkv + bkv  (bf16 out)
  gemm128<2><<<dim3((unsigned)(nmkv * (2048 / 128))), 512, 0, stream>>>(
      wvln, WkvT, bkv, nullptr, kvbuf, 2048, DD, DD, DD, 2048 / 128);
  // 5) context per (b,h)
  ctx_kernel<<<dim3(BB * HH), 256, 0, stream>>>(kvbuf, ctx);
  // 6) q column-softmax stats
  qstat_part<<<dim3(DD / 256, 32, BB), 256, 0, stream>>>(qbuf, pmax, psum);
  qstat_comb<<<dim3(BB * DD / 256), 256, 0, stream>>>(pmax, psum, cmax, crs);
  // 7) softmax-apply + per-head 64x64 matmul -> out_attn (bf16, overwrites kv)
  attn_apply<<<dim3(NN / 128, HH, BB), 256, 0, stream>>>(qbuf, ctx, cmax, crs, oattn);
  // 8) x2 = out_attn @ Wo + bo + x   (fp32, overwrites q)
  gemm128<1><<<dim3((unsigned)(nm * (DD / 128))), 512, 0, stream>>>(
      oattn, WoT, bo, x, qbuf, DD, DD, DD, DD, DD / 128);
  float* x2 = qbuf;
  // 9) LN_f(x2) -> bf16
  ln_rows<<<dim3((unsigned)MR), 256, 0, stream>>>(x2, ln_f_g, ln_f_b, lnbuf);
  // 10) MLP: h = silu(x2ln @ W1 + b1); out = x2 + h @ W2 + b2
  for (int c0 = 0; c0 < 4096; c0 += CS) {
    gemm128<3><<<dim3((unsigned)(nm * (CS / 128))), 512, 0, stream>>>(
        lnbuf, W1T + (long)c0 * DD, b1 + c0, nullptr, hbuf, CS, DD, DD, DD, CS / 128);
    gemm128<1><<<dim3((unsigned)(nm * (DD / 128))), 512, 0, stream>>>(
        hbuf, W2T + c0, (c0 == 0) ? b2 : nullptr,
        (c0 == 0) ? (const float*)x2 : (const float*)outp, outp, DD, CS, CS, 4096, DD / 128);
  }
}